// Round 10
// baseline (273.724 us; speedup 1.0000x reference)
//
#include <hip/hip_runtime.h>
#include <hip/hip_bf16.h>

#define DIM 32
#define INDIM 5
#define EPB 4096      // edges per block in bucketing passes
#define BKBITS 7
#define BKN 128       // nodes per bucket
#define NBMAX 1024    // max buckets (n <= 131072)
#define CAP 4096      // P2 LDS staging capacity (mean bucket load ~2560)

// bf16 helpers (bit-level, round-to-nearest-even)
__device__ __forceinline__ unsigned short f2bf(float f) {
    unsigned u = __float_as_uint(f);
    u += 0x7FFFu + ((u >> 16) & 1u);
    return (unsigned short)(u >> 16);
}
__device__ __forceinline__ float bf2f_lo(unsigned u) { return __uint_as_float(u << 16); }
__device__ __forceinline__ float bf2f_hi(unsigned u) { return __uint_as_float(u & 0xFFFF0000u); }

// ---------------- P0: bucket sizes ----------------

__global__ __launch_bounds__(256) void bucket_count_kernel(const int* __restrict__ dst,
                                                           int* __restrict__ bcnt, int e, int nb) {
    __shared__ int hist[NBMAX];
    int t = threadIdx.x;
    for (int i = t; i < nb; i += 256) hist[i] = 0;
    __syncthreads();
    int base = blockIdx.x * EPB;
    for (int k = 0; k < EPB; k += 256) {
        int i = base + k + t;
        if (i < e) {
            int dv = __builtin_nontemporal_load(&dst[i]);
            atomicAdd(&hist[dv >> BKBITS], 1);
        }
    }
    __syncthreads();
    for (int i = t; i < nb; i += 256) {
        int h = hist[i];
        if (h) atomicAdd(&bcnt[i], h);
    }
}

// ---------------- scan of bucket sizes (single block, 1024 threads) ----------------

__global__ void bucket_scan_kernel(const int* __restrict__ bcnt, int* __restrict__ bbase,
                                   int* __restrict__ bcur, int* __restrict__ row_ptr,
                                   int nb, int n, int e) {
    __shared__ int s[1024];
    int t = threadIdx.x;
    int v = (t < nb) ? bcnt[t] : 0;
    s[t] = v;
    __syncthreads();
    for (int o = 1; o < 1024; o <<= 1) {
        int a = (t >= o) ? s[t - o] : 0;
        __syncthreads();
        s[t] += a;
        __syncthreads();
    }
    if (t < nb) {
        int excl = s[t] - v;
        bbase[t] = excl;
        bcur[t] = excl;
    }
    if (t == 0) {
        bbase[nb] = e;
        row_ptr[n] = e;
    }
}

// ---------------- P1: bucketed scatter of packed edges ----------------
// packed word: (src << BKBITS) | (dst & (BKN-1))

__global__ __launch_bounds__(256) void bucket_fill_kernel(const int* __restrict__ src,
                                                          const int* __restrict__ dst,
                                                          int* __restrict__ bcur,
                                                          unsigned* __restrict__ packed,
                                                          int e, int nb) {
    __shared__ unsigned sw[EPB];
    __shared__ unsigned short sb[EPB];
    __shared__ int hist[NBMAX];
    __shared__ int rbase[NBMAX];
    int t = threadIdx.x;
    for (int i = t; i < nb; i += 256) hist[i] = 0;
    __syncthreads();
    int base = blockIdx.x * EPB;
    for (int k = 0; k < EPB; k += 256) {
        int i = base + k + t;
        if (i < e) {
            int s = __builtin_nontemporal_load(&src[i]);
            int d = __builtin_nontemporal_load(&dst[i]);
            int b = d >> BKBITS;
            sw[k + t] = ((unsigned)s << BKBITS) | (unsigned)(d & (BKN - 1));
            sb[k + t] = (unsigned short)b;
            atomicAdd(&hist[b], 1);
        }
    }
    __syncthreads();
    for (int i = t; i < nb; i += 256) {
        int h = hist[i];
        rbase[i] = h ? atomicAdd(&bcur[i], h) : 0;
        hist[i] = 0;  // reuse as rank counter
    }
    __syncthreads();
    for (int k = 0; k < EPB; k += 256) {
        int i = base + k + t;
        if (i < e) {
            int b = sb[k + t];
            int r = atomicAdd(&hist[b], 1);
            packed[rbase[b] + r] = sw[k + t];
        }
    }
}

// ---------------- P2: per-bucket counting sort -> exact CSR ----------------

__global__ __launch_bounds__(256) void csr_build_kernel(const unsigned* __restrict__ packed,
                                                        const int* __restrict__ bbase,
                                                        int* __restrict__ row_ptr,
                                                        int* __restrict__ esrc, int n) {
    __shared__ unsigned ew[CAP];
    __shared__ int h2[BKN];
    __shared__ int off[BKN];
    int b = blockIdx.x;
    int base = bbase[b];
    int cnt = bbase[b + 1] - base;
    int t = threadIdx.x;
    if (t < BKN) h2[t] = 0;
    __syncthreads();
    bool staged = (cnt <= CAP);
    for (int i = t; i < cnt; i += 256) {
        unsigned w = __builtin_nontemporal_load(&packed[base + i]);
        if (staged) ew[i] = w;
        atomicAdd(&h2[w & (BKN - 1)], 1);
    }
    __syncthreads();
    int v = 0;
    if (t < BKN) {
        v = h2[t];
        off[t] = v;
    }
    __syncthreads();
    for (int o = 1; o < BKN; o <<= 1) {
        int a = 0;
        if (t < BKN && t >= o) a = off[t - o];
        __syncthreads();
        if (t < BKN) off[t] += a;
        __syncthreads();
    }
    if (t < BKN) {
        int excl = off[t] - v;
        off[t] = excl;
        h2[t] = 0;  // reuse as rank counter
    }
    __syncthreads();
    int node = b * BKN + t;
    if (t < BKN && node < n) row_ptr[node] = base + off[t];
    for (int i = t; i < cnt; i += 256) {
        unsigned w = staged ? ew[i] : packed[base + i];
        int dl = w & (BKN - 1);
        int r = atomicAdd(&h2[dl], 1);
        esrc[base + off[dl] + r] = (int)(w >> BKBITS);
    }
}

// ---------------- input projection: h = x @ w_in.T + b_in (bf16, split planes) ----------------
// plane layout: lo plane [n][16] at h, hi plane [n][16] at h + n*16

__global__ void input_proj_kernel(const float* __restrict__ x, const float* __restrict__ w_in,
                                  const float* __restrict__ b_in,
                                  unsigned short* __restrict__ h, int n) {
    __shared__ float sw[DIM * INDIM];
    __shared__ float sb[DIM];
    int t = threadIdx.x;
    if (t < DIM * INDIM) sw[t] = w_in[t];
    if (t < DIM) sb[t] = b_in[t];
    __syncthreads();
    int idx = blockIdx.x * 256 + t;
    int node = idx >> 5;
    int d = idx & 31;
    if (node < n) {
        const float* xr = x + (size_t)node * INDIM;
        float acc = sb[d];
#pragma unroll
        for (int k = 0; k < INDIM; k++) acc = fmaf(xr[k], sw[d * INDIM + k], acc);
        h[(size_t)(d >> 4) * n * 16 + (size_t)node * 16 + (d & 15)] = f2bf(acc);
    }
}

// ---------------- fused layer: gather-mean + SAGEConv + ReLU + LayerNorm ----------------
// 32 nodes/block, 128 threads, h in two 16-dim planes (32 B rows).
// Phase p in {0,1}: all threads gather plane p (4 threads/node, uint2 = 4 dims each,
// 8-wide pipeline with id prefetch) -> 3.2 MB active working set, L2-resident.
// Then: dual matvec with weights in registers, ReLU + LN, direct store.

template <int LAST>
__global__ __launch_bounds__(128, 4) void layer_fused_kernel(
    const int* __restrict__ row_ptr, const int* __restrict__ esrc,
    const unsigned short* __restrict__ h_in,
    unsigned short* __restrict__ h_out_bf, float* __restrict__ out_f32,
    const float* __restrict__ wl, const float* __restrict__ bl,
    const float* __restrict__ wr, const float* __restrict__ gamma,
    const float* __restrict__ beta, int n) {
    __shared__ float sAgg[32][DIM];
    __shared__ float sSelf[32][DIM];

    int t = threadIdx.x;
    int d = t & 31;
    int nd = t >> 2;  // 0..31
    int q = t & 3;
    int node = blockIdx.x * 32 + nd;

    int rs = 0, re = 0;
    if (node < n) {
        rs = row_ptr[node];
        re = row_ptr[node + 1];
    }
    float iv = 1.f / fmaxf((float)(re - rs), 1.f);

#pragma unroll
    for (int p = 0; p < 2; ++p) {
        const uint2* hv = (const uint2*)(h_in + (size_t)p * n * 16);  // 4 uint2 per 32B row
        if (node < n) {
            {   // self slice: 4 dims of plane p
                uint2 v = hv[(size_t)node * 4 + q];
                float4 f = make_float4(bf2f_lo(v.x), bf2f_hi(v.x), bf2f_lo(v.y), bf2f_hi(v.y));
                *(float4*)&sSelf[nd][p * 16 + q * 4] = f;
            }
            float a0 = 0.f, a1 = 0.f, a2 = 0.f, a3 = 0.f;
            int j = rs;
            int i0, i1, i2, i3, i4, i5, i6, i7;
            bool have = (j + 8 <= re);
            if (have) {
                i0 = esrc[j];     i1 = esrc[j + 1]; i2 = esrc[j + 2]; i3 = esrc[j + 3];
                i4 = esrc[j + 4]; i5 = esrc[j + 5]; i6 = esrc[j + 6]; i7 = esrc[j + 7];
            }
            while (have) {
                int jn = j + 8;
                bool haven = (jn + 8 <= re);
                int t0, t1, t2, t3, t4, t5, t6, t7;
                if (haven) {  // prefetch next ids while gathering current rows
                    t0 = esrc[jn];     t1 = esrc[jn + 1]; t2 = esrc[jn + 2]; t3 = esrc[jn + 3];
                    t4 = esrc[jn + 4]; t5 = esrc[jn + 5]; t6 = esrc[jn + 6]; t7 = esrc[jn + 7];
                }
                uint2 v0 = hv[(size_t)i0 * 4 + q];
                uint2 v1 = hv[(size_t)i1 * 4 + q];
                uint2 v2 = hv[(size_t)i2 * 4 + q];
                uint2 v3 = hv[(size_t)i3 * 4 + q];
                uint2 v4 = hv[(size_t)i4 * 4 + q];
                uint2 v5 = hv[(size_t)i5 * 4 + q];
                uint2 v6 = hv[(size_t)i6 * 4 + q];
                uint2 v7 = hv[(size_t)i7 * 4 + q];
                a0 += bf2f_lo(v0.x); a1 += bf2f_hi(v0.x); a2 += bf2f_lo(v0.y); a3 += bf2f_hi(v0.y);
                a0 += bf2f_lo(v1.x); a1 += bf2f_hi(v1.x); a2 += bf2f_lo(v1.y); a3 += bf2f_hi(v1.y);
                a0 += bf2f_lo(v2.x); a1 += bf2f_hi(v2.x); a2 += bf2f_lo(v2.y); a3 += bf2f_hi(v2.y);
                a0 += bf2f_lo(v3.x); a1 += bf2f_hi(v3.x); a2 += bf2f_lo(v3.y); a3 += bf2f_hi(v3.y);
                a0 += bf2f_lo(v4.x); a1 += bf2f_hi(v4.x); a2 += bf2f_lo(v4.y); a3 += bf2f_hi(v4.y);
                a0 += bf2f_lo(v5.x); a1 += bf2f_hi(v5.x); a2 += bf2f_lo(v5.y); a3 += bf2f_hi(v5.y);
                a0 += bf2f_lo(v6.x); a1 += bf2f_hi(v6.x); a2 += bf2f_lo(v6.y); a3 += bf2f_hi(v6.y);
                a0 += bf2f_lo(v7.x); a1 += bf2f_hi(v7.x); a2 += bf2f_lo(v7.y); a3 += bf2f_hi(v7.y);
                j = jn;
                have = haven;
                if (haven) {
                    i0 = t0; i1 = t1; i2 = t2; i3 = t3; i4 = t4; i5 = t5; i6 = t6; i7 = t7;
                }
            }
            for (; j < re; ++j) {
                int s = esrc[j];
                uint2 v = hv[(size_t)s * 4 + q];
                a0 += bf2f_lo(v.x); a1 += bf2f_hi(v.x); a2 += bf2f_lo(v.y); a3 += bf2f_hi(v.y);
            }
            float4 f = make_float4(a0 * iv, a1 * iv, a2 * iv, a3 * iv);
            *(float4*)&sAgg[nd][p * 16 + q * 4] = f;
        }
    }
    __syncthreads();

    // ---- combine + ReLU + LN (weights loaded here, after the barrier) ----
    float wlr[DIM], wrr[DIM];
    {
        const float4* p1 = (const float4*)(wl + (size_t)d * DIM);
        const float4* p2 = (const float4*)(wr + (size_t)d * DIM);
#pragma unroll
        for (int qq = 0; qq < 8; qq++) {
            float4 a = p1[qq];
            wlr[4 * qq] = a.x; wlr[4 * qq + 1] = a.y; wlr[4 * qq + 2] = a.z; wlr[4 * qq + 3] = a.w;
            float4 c = p2[qq];
            wrr[4 * qq] = c.x; wrr[4 * qq + 1] = c.y; wrr[4 * qq + 2] = c.z; wrr[4 * qq + 3] = c.w;
        }
    }
    float bias = bl[d], g = gamma[d], be = beta[d];

#pragma unroll
    for (int it = 0; it < 8; ++it) {
        int ln = it * 4 + (t >> 5);           // local node 0..31
        int nodec = blockIdx.x * 32 + ln;
        if (nodec < n) {
            float o = bias;
            const float* va = sAgg[ln];
            const float* vs = sSelf[ln];
#pragma unroll
            for (int qq = 0; qq < 8; qq++) {
                float4 a = *(const float4*)&va[qq * 4];
                float4 s = *(const float4*)&vs[qq * 4];
                o = fmaf(a.x, wlr[4 * qq], o);     o = fmaf(s.x, wrr[4 * qq], o);
                o = fmaf(a.y, wlr[4 * qq + 1], o); o = fmaf(s.y, wrr[4 * qq + 1], o);
                o = fmaf(a.z, wlr[4 * qq + 2], o); o = fmaf(s.z, wrr[4 * qq + 2], o);
                o = fmaf(a.w, wlr[4 * qq + 3], o); o = fmaf(s.w, wrr[4 * qq + 3], o);
            }
            float out = fmaxf(o, 0.f);
            float sum = out, sq = out * out;
#pragma unroll
            for (int off = 16; off > 0; off >>= 1) {
                sum += __shfl_xor(sum, off, 32);
                sq += __shfl_xor(sq, off, 32);
            }
            float mu = sum * (1.f / 32.f);
            float var = fmaxf(sq * (1.f / 32.f) - mu * mu, 0.f);
            float r = rsqrtf(var + 1e-5f);
            float res = (out - mu) * r * g + be;
            if (LAST) out_f32[(size_t)nodec * DIM + d] = res;
            else      h_out_bf[(size_t)(d >> 4) * n * 16 + (size_t)nodec * 16 + (d & 15)] = f2bf(res);
        }
    }
}

// ---------------- launch ----------------

extern "C" void kernel_launch(void* const* d_in, const int* in_sizes, int n_in,
                              void* d_out, int out_size, void* d_ws, size_t ws_size,
                              hipStream_t stream) {
    const float* x = (const float*)d_in[0];
    const int* ei = (const int*)d_in[1];
    const float* w_in = (const float*)d_in[2];
    const float* b_in = (const float*)d_in[3];
    const float* w_l = (const float*)d_in[4];
    const float* b_l = (const float*)d_in[5];
    const float* w_r = (const float*)d_in[6];
    const float* gamma = (const float*)d_in[7];
    const float* beta = (const float*)d_in[8];

    int n = in_sizes[0] / INDIM;
    int e = in_sizes[1] / 2;
    int L = in_sizes[4] / (DIM * DIM);
    const int* src = ei;
    const int* dst = ei + e;
    int nb = (n + BKN - 1) >> BKBITS;  // 128-node buckets (782 for N=100000)

    // workspace carve (~21.7 MB)
    char* w = (char*)d_ws;
    int* bcnt = (int*)w;               w += (size_t)NBMAX * 4;
    int* bbase = (int*)w;              w += (size_t)(NBMAX + 1) * 4;
    int* bcur = (int*)w;               w += (size_t)NBMAX * 4;
    int* row_ptr = (int*)w;            w += (size_t)(n + 1) * 4;
    int* esrc = (int*)w;               w += (size_t)e * 4;
    unsigned short* h_A = (unsigned short*)w;  w += (size_t)n * DIM * 2;
    unsigned short* h_B = (unsigned short*)w;  w += (size_t)n * DIM * 2;
    // packed (E*4 = 8 MB) aliases h_A+h_B (12.8 MB): dead before input_proj
    unsigned* packed = (unsigned*)h_A;

    int nbE = (e + EPB - 1) / EPB;

    hipMemsetAsync(bcnt, 0, (size_t)nb * 4, stream);
    bucket_count_kernel<<<nbE, 256, 0, stream>>>(dst, bcnt, e, nb);
    bucket_scan_kernel<<<1, 1024, 0, stream>>>(bcnt, bbase, bcur, row_ptr, nb, n, e);
    bucket_fill_kernel<<<nbE, 256, 0, stream>>>(src, dst, bcur, packed, e, nb);
    csr_build_kernel<<<nb, 256, 0, stream>>>(packed, bbase, row_ptr, esrc, n);

    input_proj_kernel<<<(n * DIM + 255) / 256, 256, 0, stream>>>(x, w_in, b_in, h_A, n);

    // L=3: A->B, B->A, A->d_out
    unsigned short* bufs[2] = {h_A, h_B};
    int nbF = (n + 31) / 32;
    for (int i = 0; i < L; i++) {
        const unsigned short* hin = bufs[i & 1];
        unsigned short* hout = bufs[(i + 1) & 1];
        const float* wl = w_l + (size_t)i * DIM * DIM;
        const float* bl = b_l + (size_t)i * DIM;
        const float* wr = w_r + (size_t)i * DIM * DIM;
        if (i == L - 1)
            layer_fused_kernel<1><<<nbF, 128, 0, stream>>>(row_ptr, esrc, hin, nullptr,
                                                           (float*)d_out, wl, bl, wr,
                                                           gamma, beta, n);
        else
            layer_fused_kernel<0><<<nbF, 128, 0, stream>>>(row_ptr, esrc, hin, hout,
                                                           nullptr, wl, bl, wr,
                                                           gamma, beta, n);
    }
}

// Round 11
// 246.104 us; speedup vs baseline: 1.1122x; 1.1122x over previous
//
#include <hip/hip_runtime.h>
#include <hip/hip_bf16.h>

#define DIM 32
#define INDIM 5
#define EPB 4096      // edges per block in bucketing passes
#define BKBITS 7
#define BKN 128       // nodes per bucket
#define NBMAX 1024    // max buckets (n <= 131072)
#define CAP 4096      // P2 LDS staging capacity (mean bucket load ~2560)

// bf16 helpers (bit-level, round-to-nearest-even)
__device__ __forceinline__ unsigned short f2bf(float f) {
    unsigned u = __float_as_uint(f);
    u += 0x7FFFu + ((u >> 16) & 1u);
    return (unsigned short)(u >> 16);
}
__device__ __forceinline__ float bf2f_lo(unsigned u) { return __uint_as_float(u << 16); }
__device__ __forceinline__ float bf2f_hi(unsigned u) { return __uint_as_float(u & 0xFFFF0000u); }

// packed accumulate: 8 bf16 dims of one uint4 into 4 float2 accumulators
// (2 unpack VALU + 1 v_pk_add_f32 per 2 dims; per-dim add order preserved)
__device__ __forceinline__ void acc_pk(float2& a01, float2& a23, float2& a45, float2& a67,
                                       uint4 v) {
    float2 v01, v23, v45, v67;
    v01.x = bf2f_lo(v.x); v01.y = bf2f_hi(v.x);
    v23.x = bf2f_lo(v.y); v23.y = bf2f_hi(v.y);
    v45.x = bf2f_lo(v.z); v45.y = bf2f_hi(v.z);
    v67.x = bf2f_lo(v.w); v67.y = bf2f_hi(v.w);
    asm volatile("v_pk_add_f32 %0, %0, %1" : "+v"(a01) : "v"(v01));
    asm volatile("v_pk_add_f32 %0, %0, %1" : "+v"(a23) : "v"(v23));
    asm volatile("v_pk_add_f32 %0, %0, %1" : "+v"(a45) : "v"(v45));
    asm volatile("v_pk_add_f32 %0, %0, %1" : "+v"(a67) : "v"(v67));
}

// ---------------- P0: bucket sizes ----------------

__global__ __launch_bounds__(256) void bucket_count_kernel(const int* __restrict__ dst,
                                                           int* __restrict__ bcnt, int e, int nb) {
    __shared__ int hist[NBMAX];
    int t = threadIdx.x;
    for (int i = t; i < nb; i += 256) hist[i] = 0;
    __syncthreads();
    int base = blockIdx.x * EPB;
    for (int k = 0; k < EPB; k += 256) {
        int i = base + k + t;
        if (i < e) {
            int dv = __builtin_nontemporal_load(&dst[i]);
            atomicAdd(&hist[dv >> BKBITS], 1);
        }
    }
    __syncthreads();
    for (int i = t; i < nb; i += 256) {
        int h = hist[i];
        if (h) atomicAdd(&bcnt[i], h);
    }
}

// ---------------- scan of bucket sizes (single block, 1024 threads) ----------------

__global__ void bucket_scan_kernel(const int* __restrict__ bcnt, int* __restrict__ bbase,
                                   int* __restrict__ bcur, int* __restrict__ row_ptr,
                                   int nb, int n, int e) {
    __shared__ int s[1024];
    int t = threadIdx.x;
    int v = (t < nb) ? bcnt[t] : 0;
    s[t] = v;
    __syncthreads();
    for (int o = 1; o < 1024; o <<= 1) {
        int a = (t >= o) ? s[t - o] : 0;
        __syncthreads();
        s[t] += a;
        __syncthreads();
    }
    if (t < nb) {
        int excl = s[t] - v;
        bbase[t] = excl;
        bcur[t] = excl;
    }
    if (t == 0) {
        bbase[nb] = e;
        row_ptr[n] = e;
    }
}

// ---------------- P1: bucketed scatter of packed edges ----------------
// packed word: (src << BKBITS) | (dst & (BKN-1))

__global__ __launch_bounds__(256) void bucket_fill_kernel(const int* __restrict__ src,
                                                          const int* __restrict__ dst,
                                                          int* __restrict__ bcur,
                                                          unsigned* __restrict__ packed,
                                                          int e, int nb) {
    __shared__ unsigned sw[EPB];
    __shared__ unsigned short sb[EPB];
    __shared__ int hist[NBMAX];
    __shared__ int rbase[NBMAX];
    int t = threadIdx.x;
    for (int i = t; i < nb; i += 256) hist[i] = 0;
    __syncthreads();
    int base = blockIdx.x * EPB;
    for (int k = 0; k < EPB; k += 256) {
        int i = base + k + t;
        if (i < e) {
            int s = __builtin_nontemporal_load(&src[i]);
            int d = __builtin_nontemporal_load(&dst[i]);
            int b = d >> BKBITS;
            sw[k + t] = ((unsigned)s << BKBITS) | (unsigned)(d & (BKN - 1));
            sb[k + t] = (unsigned short)b;
            atomicAdd(&hist[b], 1);
        }
    }
    __syncthreads();
    for (int i = t; i < nb; i += 256) {
        int h = hist[i];
        rbase[i] = h ? atomicAdd(&bcur[i], h) : 0;
        hist[i] = 0;  // reuse as rank counter
    }
    __syncthreads();
    for (int k = 0; k < EPB; k += 256) {
        int i = base + k + t;
        if (i < e) {
            int b = sb[k + t];
            int r = atomicAdd(&hist[b], 1);
            packed[rbase[b] + r] = sw[k + t];
        }
    }
}

// ---------------- P2: per-bucket counting sort -> exact CSR ----------------

__global__ __launch_bounds__(256) void csr_build_kernel(const unsigned* __restrict__ packed,
                                                        const int* __restrict__ bbase,
                                                        int* __restrict__ row_ptr,
                                                        int* __restrict__ esrc, int n) {
    __shared__ unsigned ew[CAP];
    __shared__ int h2[BKN];
    __shared__ int off[BKN];
    int b = blockIdx.x;
    int base = bbase[b];
    int cnt = bbase[b + 1] - base;
    int t = threadIdx.x;
    if (t < BKN) h2[t] = 0;
    __syncthreads();
    bool staged = (cnt <= CAP);
    for (int i = t; i < cnt; i += 256) {
        unsigned w = __builtin_nontemporal_load(&packed[base + i]);
        if (staged) ew[i] = w;
        atomicAdd(&h2[w & (BKN - 1)], 1);
    }
    __syncthreads();
    int v = 0;
    if (t < BKN) {
        v = h2[t];
        off[t] = v;
    }
    __syncthreads();
    for (int o = 1; o < BKN; o <<= 1) {
        int a = 0;
        if (t < BKN && t >= o) a = off[t - o];
        __syncthreads();
        if (t < BKN) off[t] += a;
        __syncthreads();
    }
    if (t < BKN) {
        int excl = off[t] - v;
        off[t] = excl;
        h2[t] = 0;  // reuse as rank counter
    }
    __syncthreads();
    int node = b * BKN + t;
    if (t < BKN && node < n) row_ptr[node] = base + off[t];
    for (int i = t; i < cnt; i += 256) {
        unsigned w = staged ? ew[i] : packed[base + i];
        int dl = w & (BKN - 1);
        int r = atomicAdd(&h2[dl], 1);
        esrc[base + off[dl] + r] = (int)(w >> BKBITS);
    }
}

// ---------------- input projection: h = x @ w_in.T + b_in (bf16 out) ----------------

__global__ void input_proj_kernel(const float* __restrict__ x, const float* __restrict__ w_in,
                                  const float* __restrict__ b_in,
                                  unsigned short* __restrict__ h, int n) {
    __shared__ float sw[DIM * INDIM];
    __shared__ float sb[DIM];
    int t = threadIdx.x;
    if (t < DIM * INDIM) sw[t] = w_in[t];
    if (t < DIM) sb[t] = b_in[t];
    __syncthreads();
    int idx = blockIdx.x * 256 + t;
    int node = idx >> 5;
    int d = idx & 31;
    if (node < n) {
        const float* xr = x + (size_t)node * INDIM;
        float acc = sb[d];
#pragma unroll
        for (int k = 0; k < INDIM; k++) acc = fmaf(xr[k], sw[d * INDIM + k], acc);
        h[(size_t)node * DIM + d] = f2bf(acc);
    }
}

// ---------------- fused layer: gather-mean + SAGEConv + ReLU + LayerNorm ----------------
// 32 nodes/block, 128 threads. Phase 1: 4 threads/node (thread q owns dims [8q,8q+8)),
// 16-wide pull gather with id-prefetch pipeline + 8-wide step + scalar tail,
// packed v_pk_add_f32 accumulate. Phase 2: dual matvec with both weight matrices in
// registers (loaded after the barrier), ReLU + LN, direct store.

template <int LAST>
__global__ __launch_bounds__(128, 3) void layer_fused_kernel(
    const int* __restrict__ row_ptr, const int* __restrict__ esrc,
    const unsigned short* __restrict__ h_in,
    unsigned short* __restrict__ h_out_bf, float* __restrict__ out_f32,
    const float* __restrict__ wl, const float* __restrict__ bl,
    const float* __restrict__ wr, const float* __restrict__ gamma,
    const float* __restrict__ beta, int n) {
    __shared__ float sAgg[32][DIM];
    __shared__ float sSelf[32][DIM];

    int t = threadIdx.x;
    int d = t & 31;

    // ---- phase 1: gather ----
    int nd = t >> 2;  // 0..31
    int q = t & 3;
    int node = blockIdx.x * 32 + nd;
    const uint4* hv = (const uint4*)h_in;  // row = 4 x uint4 (64 B)

    if (node < n) {
        {
            uint4 v = hv[(size_t)node * 4 + q];
            float4 f0 = make_float4(bf2f_lo(v.x), bf2f_hi(v.x), bf2f_lo(v.y), bf2f_hi(v.y));
            float4 f1 = make_float4(bf2f_lo(v.z), bf2f_hi(v.z), bf2f_lo(v.w), bf2f_hi(v.w));
            *(float4*)&sSelf[nd][q * 8] = f0;
            *(float4*)&sSelf[nd][q * 8 + 4] = f1;
        }
        int rs = row_ptr[node];
        int re = row_ptr[node + 1];
        float2 a01 = make_float2(0.f, 0.f), a23 = make_float2(0.f, 0.f);
        float2 a45 = make_float2(0.f, 0.f), a67 = make_float2(0.f, 0.f);
        int j = rs;
        int ids[16];
        bool have = (j + 16 <= re);
        if (have) {
#pragma unroll
            for (int k = 0; k < 16; k++) ids[k] = esrc[j + k];
        }
        while (have) {
            int jn = j + 16;
            bool haven = (jn + 16 <= re);
            uint4 vv[16];
#pragma unroll
            for (int k = 0; k < 16; k++) vv[k] = hv[(size_t)ids[k] * 4 + q];
            int nids[16];
            if (haven) {  // prefetch next ids while current rows are in flight
#pragma unroll
                for (int k = 0; k < 16; k++) nids[k] = esrc[jn + k];
            }
#pragma unroll
            for (int k = 0; k < 16; k++) acc_pk(a01, a23, a45, a67, vv[k]);
            j = jn;
            have = haven;
            if (haven) {
#pragma unroll
                for (int k = 0; k < 16; k++) ids[k] = nids[k];
            }
        }
        if (j + 8 <= re) {
            int id8[8];
#pragma unroll
            for (int k = 0; k < 8; k++) id8[k] = esrc[j + k];
            uint4 vv[8];
#pragma unroll
            for (int k = 0; k < 8; k++) vv[k] = hv[(size_t)id8[k] * 4 + q];
#pragma unroll
            for (int k = 0; k < 8; k++) acc_pk(a01, a23, a45, a67, vv[k]);
            j += 8;
        }
        for (; j < re; ++j) {
            int s = esrc[j];
            uint4 v = hv[(size_t)s * 4 + q];
            acc_pk(a01, a23, a45, a67, v);
        }
        float iv = 1.f / fmaxf((float)(re - rs), 1.f);
        float4 f0 = make_float4(a01.x * iv, a01.y * iv, a23.x * iv, a23.y * iv);
        float4 f1 = make_float4(a45.x * iv, a45.y * iv, a67.x * iv, a67.y * iv);
        *(float4*)&sAgg[nd][q * 8] = f0;
        *(float4*)&sAgg[nd][q * 8 + 4] = f1;
    }
    __syncthreads();

    // ---- phase 2: combine + ReLU + LN (weights loaded here, after the barrier) ----
    float wlr[DIM], wrr[DIM];
    {
        const float4* p1 = (const float4*)(wl + (size_t)d * DIM);
        const float4* p2 = (const float4*)(wr + (size_t)d * DIM);
#pragma unroll
        for (int qq = 0; qq < 8; qq++) {
            float4 a = p1[qq];
            wlr[4 * qq] = a.x; wlr[4 * qq + 1] = a.y; wlr[4 * qq + 2] = a.z; wlr[4 * qq + 3] = a.w;
            float4 c = p2[qq];
            wrr[4 * qq] = c.x; wrr[4 * qq + 1] = c.y; wrr[4 * qq + 2] = c.z; wrr[4 * qq + 3] = c.w;
        }
    }
    float bias = bl[d], g = gamma[d], be = beta[d];

#pragma unroll
    for (int it = 0; it < 8; ++it) {
        int ln = it * 4 + (t >> 5);           // local node 0..31
        int nodec = blockIdx.x * 32 + ln;
        if (nodec < n) {
            float o = bias;
            const float* va = sAgg[ln];
            const float* vs = sSelf[ln];
#pragma unroll
            for (int qq = 0; qq < 8; qq++) {
                float4 a = *(const float4*)&va[qq * 4];
                float4 s = *(const float4*)&vs[qq * 4];
                o = fmaf(a.x, wlr[4 * qq], o);     o = fmaf(s.x, wrr[4 * qq], o);
                o = fmaf(a.y, wlr[4 * qq + 1], o); o = fmaf(s.y, wrr[4 * qq + 1], o);
                o = fmaf(a.z, wlr[4 * qq + 2], o); o = fmaf(s.z, wrr[4 * qq + 2], o);
                o = fmaf(a.w, wlr[4 * qq + 3], o); o = fmaf(s.w, wrr[4 * qq + 3], o);
            }
            float out = fmaxf(o, 0.f);
            float sum = out, sq = out * out;
#pragma unroll
            for (int off = 16; off > 0; off >>= 1) {
                sum += __shfl_xor(sum, off, 32);
                sq += __shfl_xor(sq, off, 32);
            }
            float mu = sum * (1.f / 32.f);
            float var = fmaxf(sq * (1.f / 32.f) - mu * mu, 0.f);
            float r = rsqrtf(var + 1e-5f);
            float res = (out - mu) * r * g + be;
            if (LAST) out_f32[(size_t)nodec * DIM + d] = res;
            else      h_out_bf[(size_t)nodec * DIM + d] = f2bf(res);
        }
    }
}

// ---------------- launch ----------------

extern "C" void kernel_launch(void* const* d_in, const int* in_sizes, int n_in,
                              void* d_out, int out_size, void* d_ws, size_t ws_size,
                              hipStream_t stream) {
    const float* x = (const float*)d_in[0];
    const int* ei = (const int*)d_in[1];
    const float* w_in = (const float*)d_in[2];
    const float* b_in = (const float*)d_in[3];
    const float* w_l = (const float*)d_in[4];
    const float* b_l = (const float*)d_in[5];
    const float* w_r = (const float*)d_in[6];
    const float* gamma = (const float*)d_in[7];
    const float* beta = (const float*)d_in[8];

    int n = in_sizes[0] / INDIM;
    int e = in_sizes[1] / 2;
    int L = in_sizes[4] / (DIM * DIM);
    const int* src = ei;
    const int* dst = ei + e;
    int nb = (n + BKN - 1) >> BKBITS;  // 128-node buckets (782 for N=100000)

    // workspace carve (~21.7 MB)
    char* w = (char*)d_ws;
    int* bcnt = (int*)w;               w += (size_t)NBMAX * 4;
    int* bbase = (int*)w;              w += (size_t)(NBMAX + 1) * 4;
    int* bcur = (int*)w;               w += (size_t)NBMAX * 4;
    int* row_ptr = (int*)w;            w += (size_t)(n + 1) * 4;
    int* esrc = (int*)w;               w += (size_t)e * 4;
    unsigned short* h_A = (unsigned short*)w;  w += (size_t)n * DIM * 2;
    unsigned short* h_B = (unsigned short*)w;  w += (size_t)n * DIM * 2;
    // packed (E*4 = 8 MB) aliases h_A+h_B (12.8 MB): dead before input_proj
    unsigned* packed = (unsigned*)h_A;

    int nbE = (e + EPB - 1) / EPB;

    hipMemsetAsync(bcnt, 0, (size_t)nb * 4, stream);
    bucket_count_kernel<<<nbE, 256, 0, stream>>>(dst, bcnt, e, nb);
    bucket_scan_kernel<<<1, 1024, 0, stream>>>(bcnt, bbase, bcur, row_ptr, nb, n, e);
    bucket_fill_kernel<<<nbE, 256, 0, stream>>>(src, dst, bcur, packed, e, nb);
    csr_build_kernel<<<nb, 256, 0, stream>>>(packed, bbase, row_ptr, esrc, n);

    input_proj_kernel<<<(n * DIM + 255) / 256, 256, 0, stream>>>(x, w_in, b_in, h_A, n);

    // L=3: A->B, B->A, A->d_out
    unsigned short* bufs[2] = {h_A, h_B};
    int nbF = (n + 31) / 32;
    for (int i = 0; i < L; i++) {
        const unsigned short* hin = bufs[i & 1];
        unsigned short* hout = bufs[(i + 1) & 1];
        const float* wl = w_l + (size_t)i * DIM * DIM;
        const float* bl = b_l + (size_t)i * DIM;
        const float* wr = w_r + (size_t)i * DIM * DIM;
        if (i == L - 1)
            layer_fused_kernel<1><<<nbF, 128, 0, stream>>>(row_ptr, esrc, hin, nullptr,
                                                           (float*)d_out, wl, bl, wr,
                                                           gamma, beta, n);
        else
            layer_fused_kernel<0><<<nbF, 128, 0, stream>>>(row_ptr, esrc, hin, hout,
                                                           nullptr, wl, bl, wr,
                                                           gamma, beta, n);
    }
}